// Round 5
// baseline (236.482 us; speedup 1.0000x reference)
//
#include <hip/hip_runtime.h>

#define L_DIM 256
#define M_DIM 512
#define Q_DIM 21
#define BLKB   1764         // bytes per 21x21 J block
#define SLOT   1920         // LDS slot: 1792B J window + 64B idx + pad (16B aligned)
#define IDXOFF 1792
#define NBUF   4
#define DEPTH  3            // stage col j+DEPTH at iter j; wait vmcnt(3*DEPTH)

#define GLD(src, dst, sz) __builtin_amdgcn_global_load_lds( \
    (const __attribute__((address_space(1))) void*)(src),   \
    (__attribute__((address_space(3))) void*)(dst), sz, 0, 0)

// ---- prep: one-hot -> u16 byte-offset table  Xt[j*512 + m] = 84 * argmax ----
__global__ __launch_bounds__(64) void ardca_prep(const float* __restrict__ X_oh,
                                                 unsigned short* __restrict__ Xt) {
  int w = blockIdx.x;                       // 2048 waves, 64 one-hot rows each
  int lane = threadIdx.x;
  const float* base = X_oh + (size_t)w * (64 * Q_DIM);   // 1344 floats
  int rowbase = w * 64;                     // global row id = m*256 + j
#pragma unroll 4
  for (int p = 0; p < 22; ++p) {
    int f = p * 63 + lane;
    float v = (lane < 63 && f < 1344) ? base[f] : 0.0f;
    unsigned long long mask = __ballot(v > 0.5f);
    if (lane < 3) {
      int rloc = 3 * p + lane;
      if (rloc < 64) {
        unsigned int bits = (unsigned int)((mask >> (21 * lane)) & 0x1FFFFFu);
        int x = bits ? __builtin_ctz(bits) : 0;
        int rr = rowbase + rloc;
        int m = rr >> 8, j = rr & 255;
        Xt[j * M_DIM + m] = (unsigned short)(x * 84);
      }
    }
  }
}

// ---- main: out[m,i,a] = h[i,a] + sum_{j<i} J[i,j,x_mj,a] ----
// 4096 single-wave blocks; lane = (a-half, m); ring-4 counted-vmcnt pipeline.
template <int USE_XT>
__global__ __launch_bounds__(64) void ardca_main(const float* __restrict__ Jm,
                                                 const float* __restrict__ h,
                                                 const unsigned short* __restrict__ Xt,
                                                 const float* __restrict__ X_oh,
                                                 float* __restrict__ out) {
  alignas(16) __shared__ char lds[NBUF * SLOT];   // 7680 B -> 16 blocks/CU
  int b = blockIdx.x;
  int c = b & 7;                 // XCD (dispatch round-robin)
  int r = b >> 3;                // 0..511
  int mg = r & 15;               // m-group of 32
  int i = ((31 - (r >> 4)) << 3) | c;   // i == c (mod 8), descending
  int lane = threadIdx.x;
  int ml = lane & 31;            // m within group
  int ah = lane >> 5;            // column half: 0 -> floats 0..11, 1 -> 12..20
  int m = mg * 32 + ml;

  const char* Jrow = (const char*)Jm + (size_t)i * (256ull * BLKB); // 16B-aligned
  const char* XtB  = (const char*)Xt;

  float acc[12];
  const float* hp = h + i * Q_DIM + ah * 12;
#pragma unroll
  for (int k = 0; k < 12; ++k) acc[k] = (ah == 0 || k < 9) ? hp[k] : 0.0f;

  auto STAGE = [&](int j) {
    char* buf = lds + (j & (NBUF - 1)) * SLOT;
    unsigned bb = (unsigned)j * BLKB;
    const char* src = Jrow + (bb & ~15u);           // 16B-aligned window
    GLD(src + lane * 16, buf, 16);                  // 1024 B
    if (lane < 48) GLD(src + 1024 + lane * 16, buf + 1024, 16);   // 768 B
    if (USE_XT) {
      if (lane < 16) GLD(XtB + j * 1024 + mg * 64 + lane * 4, buf + IDXOFF, 4);
    }
  };

  auto CONSUME = [&](int j) {
    const char* buf = lds + (j & (NBUF - 1)) * SLOT;
    int off;
    if (USE_XT) {
      off = *(const unsigned short*)(buf + IDXOFF + 2 * ml);      // 84*x, staged
    } else {
      const float* p = X_oh + ((size_t)m * L_DIM + j) * Q_DIM;
      int x = 0;
#pragma unroll
      for (int a = 0; a < Q_DIM; ++a) x = (p[a] > 0.5f) ? a : x;
      off = x * 84;
    }
    // window alignment delta: (j*1764) & 15 == (j&3)*4
    const float* row = (const float*)(buf + ((j & 3) << 2) + off) + ah * 12;
#pragma unroll
    for (int k = 0; k < 12; ++k) acc[k] += row[k];  // merges to ds_read2_b32
  };

  int P = (i < DEPTH) ? i : DEPTH;
  for (int j = 0; j < P; ++j) STAGE(j);
  int jt = i - DEPTH; if (jt < 0) jt = 0;

#pragma unroll 1
  for (int j = 0; j < jt; ++j) {
    STAGE(j + DEPTH);
    if (USE_XT) {
      asm volatile("s_waitcnt vmcnt(9)" ::: "memory");   // 3*DEPTH newer in flight
    } else {
      asm volatile("s_waitcnt vmcnt(0)" ::: "memory");
    }
    __builtin_amdgcn_sched_barrier(0);
    CONSUME(j);
  }
  asm volatile("s_waitcnt vmcnt(0)" ::: "memory");
  __builtin_amdgcn_sched_barrier(0);
#pragma unroll 1
  for (int j = jt; j < i; ++j) CONSUME(j);

  float* o = out + ((size_t)m * L_DIM + i) * Q_DIM + ah * 12;
  if (ah == 0) {
#pragma unroll
    for (int k = 0; k < 12; ++k) o[k] = acc[k];
  } else {
#pragma unroll
    for (int k = 0; k < 9; ++k) o[k] = acc[k];
  }
}

extern "C" void kernel_launch(void* const* d_in, const int* in_sizes, int n_in,
                              void* d_out, int out_size, void* d_ws, size_t ws_size,
                              hipStream_t stream) {
  const float* X_oh = (const float*)d_in[0];
  const float* h    = (const float*)d_in[1];
  const float* Jm   = (const float*)d_in[2];
  float* out        = (float*)d_out;
  unsigned short* Xt = (unsigned short*)d_ws;          // 262144 B

  if (ws_size >= (size_t)M_DIM * L_DIM * sizeof(unsigned short)) {
    ardca_prep<<<2048, 64, 0, stream>>>(X_oh, Xt);
    ardca_main<1><<<4096, 64, 0, stream>>>(Jm, h, Xt, X_oh, out);
  } else {
    ardca_main<0><<<4096, 64, 0, stream>>>(Jm, h, Xt, X_oh, out);
  }
}

// Round 6
// 223.017 us; speedup vs baseline: 1.0604x; 1.0604x over previous
//
#include <hip/hip_runtime.h>

#define Q_DIM 21
#define BLKB  1764          // bytes per 21x21 J block
#define WINB  1792          // staged J window (16B-aligned superset of one block)
#define SLOT  2304          // WINB + 512B idx
#define NBUF  6             // ring depth: write-after-read distance = 3 barriers
#define DEPTH 3             // stage col j+DEPTH at iter j; wait vmcnt(3)

#define GLD(src, dst, sz) __builtin_amdgcn_global_load_lds( \
    (const __attribute__((address_space(1))) void*)(src),   \
    (__attribute__((address_space(3))) void*)(dst), sz, 0, 0)

// ---- prep: one-hot -> u16 byte-offset table  Xt[j*512 + m] = 84 * argmax ----
// 4096 waves x 32 rows; 11 fully-independent coalesced loads per wave.
__global__ __launch_bounds__(64) void ardca_prep(const float* __restrict__ X_oh,
                                                 unsigned short* __restrict__ Xt) {
  int w = blockIdx.x;
  int lane = threadIdx.x;
  const float* base = X_oh + (size_t)w * (32 * Q_DIM);   // 672 floats
  int rowbase = w * 32;                                  // row id = m*256 + j
#pragma unroll
  for (int p = 0; p < 11; ++p) {
    int f = p * 63 + lane;
    float v = (lane < 63 && f < 672) ? base[f] : 0.0f;
    unsigned long long mask = __ballot(v > 0.5f);
    if (lane < 3) {
      int rloc = 3 * p + lane;
      if (rloc < 32) {
        unsigned int bits = (unsigned int)((mask >> (21 * lane)) & 0x1FFFFFu);
        int x = bits ? __builtin_ctz(bits) : 0;
        int rr = rowbase + rloc;
        int m = rr >> 8, j = rr & 255;
        Xt[j * 512 + m] = (unsigned short)(x * 84);
      }
    }
  }
}

// ---- main: out[m,i,a] = h[i,a] + sum_{j<i} J[i,j,x_mj,a] ----
// 512 blocks x 512 threads: block=(i, m-half); J staged ONCE per block (G=2).
// 8-wave ring-6 counted-vmcnt pipeline with raw s_barrier (never drains vmcnt).
template <int USE_XT>
__global__ __launch_bounds__(512, 4) void ardca_main(const float* __restrict__ Jm,
                                                     const float* __restrict__ h,
                                                     const unsigned short* __restrict__ Xt,
                                                     const float* __restrict__ X_oh,
                                                     float* __restrict__ out) {
  alignas(16) __shared__ char lds[NBUF * SLOT];          // 13.8 KB
  int b = blockIdx.x;
  int i, mh;
  if (b < 256) { i = b; mh = 0; }                        // i == b (mod 8) -> XCD b%8
  else { int x = b - 256; i = 248 - (x & ~7) + (x & 7); mh = 1; }  // pair: i1+i2 ~ 255
  int tid = threadIdx.x;
  int ml = tid & 255;            // m within half
  int ah = tid >> 8;             // column half: 0 -> floats 0..11, 1 -> 12..20
  int m = mh * 256 + ml;

  const char* Jrow = (const char*)Jm + (size_t)i * (256ull * BLKB);
  const char* XtB  = (const char*)Xt;

  const float* hp = h + i * Q_DIM + ah * 12;
  float acc[12];
#pragma unroll
  for (int k = 0; k < 12; ++k)
    acc[k] = (k < 9 || ah == 0) ? hp[k] : 0.0f;          // guard h OOB at i=255,ah=1

  auto STAGE = [&](int j) {
    char* buf = lds + (j % NBUF) * SLOT;
    unsigned bb = (unsigned)j * BLKB;
    const char* src = Jrow + (bb & ~15u);                // 16B-aligned window
    if (tid < 112) GLD(src + tid * 16, buf + tid * 16, 16);      // 1792 B J
    if (USE_XT) {
      if (tid >= 128 && tid < 160)                       // 512 B idx (256 u16)
        GLD(XtB + j * 1024 + mh * 512 + (tid - 128) * 16,
            buf + WINB + (tid - 128) * 16, 16);
    }
  };

  auto CONSUME = [&](int j) {
    const char* buf = lds + (j % NBUF) * SLOT;
    int off;
    if (USE_XT) {
      off = *(const unsigned short*)(buf + WINB + 2 * ml);       // 84*x, staged
    } else {
      const float* p = X_oh + ((size_t)m * 256 + j) * Q_DIM;
      int x = 0;
#pragma unroll
      for (int a = 0; a < Q_DIM; ++a) x = (p[a] > 0.5f) ? a : x;
      off = x * 84;
    }
    // window misalignment delta: (j*1764) & 15 == (j&3)*4
    const float* row = (const float*)(buf + ((j & 3) << 2) + off + ah * 48);
#pragma unroll
    for (int k = 0; k < 12; ++k) acc[k] += row[k];       // ah=1: acc[9..11] unused
  };

  int P = (i < DEPTH) ? i : DEPTH;
  for (int j = 0; j < P; ++j) STAGE(j);
  int jt = i - DEPTH; if (jt < 0) jt = 0;

#pragma unroll 1
  for (int j = 0; j < jt; ++j) {
    STAGE(j + DEPTH);
    if (USE_XT) asm volatile("s_waitcnt vmcnt(3)" ::: "memory");  // counted, never 0
    else        asm volatile("s_waitcnt vmcnt(0)" ::: "memory");
    __builtin_amdgcn_sched_barrier(0);
    __builtin_amdgcn_s_barrier();                        // raw: no vmcnt drain
    CONSUME(j);
  }
  asm volatile("s_waitcnt vmcnt(0)" ::: "memory");
  __builtin_amdgcn_sched_barrier(0);
  __builtin_amdgcn_s_barrier();
#pragma unroll 1
  for (int j = jt; j < i; ++j) CONSUME(j);

  float* o = out + ((size_t)m * 256 + i) * Q_DIM + ah * 12;
  if (ah == 0) {
#pragma unroll
    for (int k = 0; k < 12; ++k) o[k] = acc[k];
  } else {
#pragma unroll
    for (int k = 0; k < 9; ++k) o[k] = acc[k];
  }
}

extern "C" void kernel_launch(void* const* d_in, const int* in_sizes, int n_in,
                              void* d_out, int out_size, void* d_ws, size_t ws_size,
                              hipStream_t stream) {
  const float* X_oh = (const float*)d_in[0];
  const float* h    = (const float*)d_in[1];
  const float* Jm   = (const float*)d_in[2];
  float* out        = (float*)d_out;
  unsigned short* Xt = (unsigned short*)d_ws;            // 262144 B

  if (ws_size >= 262144) {
    ardca_prep<<<4096, 64, 0, stream>>>(X_oh, Xt);
    ardca_main<1><<<512, 512, 0, stream>>>(Jm, h, Xt, X_oh, out);
  } else {
    ardca_main<0><<<512, 512, 0, stream>>>(Jm, h, Xt, X_oh, out);
  }
}